// Round 6
// baseline (6535.638 us; speedup 1.0000x reference)
//
#include <hip/hip_runtime.h>
#include <math.h>

// ---------------- problem constants ----------------
#define EPSP 5.0f
#define BNEPS 1e-5f
constexpr int B_  = 64;    // batch
constexpr int T_  = 768;   // timesteps in
constexpr int D_  = 128;   // input feature
constexpr int E_  = 64;    // embedding (conv out channels)
constexpr int H_  = 128;   // hidden
constexpr int FH_ = 512;   // 4*H
constexpr int TC_ = 256;   // conv output steps
constexpr int O_  = 10;    // output classes

// ---------------- workspace layout (floats) ----------------
constexpr size_t EMB_OFF   = 0;                                  // B*TC*E
constexpr size_t SUM_OFF   = EMB_OFF + (size_t)B_ * TC_ * E_;    // 128
constexpr size_t SCL_OFF   = SUM_OFF + 128;                      // 128
constexpr size_t CWT_OFF   = SCL_OFF + 128;                      // 24576 [k][d][e]
constexpr size_t WHIF_OFF  = CWT_OFF + (size_t)E_ * D_ * 3;      // 32768 floats: w_hh bf16-hi frags (1024 thr x 64 bf16)
constexpr size_t WLO8F_OFF = WHIF_OFF + 32768;                   // 16384 floats: w_hh fp8-lo frags (1024 thr x 64 B)
constexpr size_t WTHI_OFF  = WLO8F_OFF + 16384;                  // unused gap
constexpr size_t WTLO8_OFF = WTHI_OFF + 12288;                   // unused gap
constexpr size_t ZX_OFF    = WTLO8_OFF + 6144;                   // B*TC*FH
constexpr size_t WS_FLOATS = ZX_OFF + (size_t)B_ * TC_ * FH_;    // < proven 9,560,320 capacity

typedef __bf16 bf16x8 __attribute__((ext_vector_type(8)));
typedef float  floatx4 __attribute__((ext_vector_type(4)));

__device__ inline float fast_rcp(float x) { return __builtin_amdgcn_rcpf(x); }
__device__ inline float frsq(float x) { return __builtin_amdgcn_rsqf(x); }
__device__ inline float fexp2(float x) { return __builtin_amdgcn_exp2f(x); }
__device__ inline float rl(float v, int lane) {
  return __int_as_float(__builtin_amdgcn_readlane(__float_as_int(v), lane));
}
#define LOG2E 1.4426950408889634f
__device__ inline float fsigmoid(float x) { return fast_rcp(1.f + fexp2(-LOG2E * x)); }
__device__ inline float ftanh(float x) { return 1.f - 2.f * fast_rcp(1.f + fexp2(2.f * LOG2E * x)); }

// fp8 e4m3fn encode (truncating, flush-to-zero below 2^-6). Values pre-scaled to normal range.
__device__ inline unsigned char enc8(float v) {
  unsigned b = __float_as_uint(v);
  unsigned s = b >> 31;
  int e = (int)((b >> 23) & 0xFF) - 127;
  if (e < -6) return 0;
  unsigned m3 = (b >> 20) & 7;
  return (unsigned char)((s << 7) | ((unsigned)(e + 7) << 3) | m3);
}
#define S18 3.814697265625e-06f     // 2^-18

// ---------------- prep: weight repack (w_hh frags + conv image) ----------------
// NEW layout for the 1024-thread scan: thread st (0..1023) = wave wv(0..15) x lane;
// frag f (0..7) = rti(0..1)*4 + kt; row R = wv*32 + rti*16 + m; k = kt*32 + q*8 + j.
__global__ void prep_kernel(const float* __restrict__ conv_w,
                            const float* __restrict__ w_hh,
                            float* __restrict__ ws) {
  int gid = blockIdx.x * blockDim.x + threadIdx.x;
  int nthr = gridDim.x * blockDim.x;
  for (int i = gid; i < 128; i += nthr) ws[SUM_OFF + i] = 0.f;
  __bf16* whiF = (__bf16*)(ws + WHIF_OFF);
  unsigned char* wlo8F = (unsigned char*)(ws + WLO8F_OFF);
  for (int s = gid; s < 1024 * 64; s += nthr) {
    int st = s >> 6, r2 = s & 63, f = r2 >> 3, j = r2 & 7;
    int wv = st >> 6, lane = st & 63, m = lane & 15, q = lane >> 4;
    int rti = f >> 2, kt = f & 3;
    int R = wv * 32 + rti * 16 + m;
    int k = kt * 32 + q * 8 + j;
    float w = w_hh[(size_t)R * 128 + k];
    __bf16 hi = (__bf16)w;
    whiF[s] = hi;
    wlo8F[s] = enc8((w - (float)hi) * 16384.f);
  }
  // conv_w [e][d][k] -> [k][d][e]
  for (int s = gid; s < E_ * D_ * 3; s += nthr) {
    int e = s / 384; int r = s - e * 384; int d = r / 3; int k = r - d * 3;
    ws[CWT_OFF + ((size_t)k * D_ + d) * E_ + e] = conv_w[s];
  }
}

// ---------------- conv + L2-normalize + BN partial sums ----------------
__global__ __launch_bounds__(256) void conv_bn_kernel(const float* __restrict__ inputs,
                                                      const float* __restrict__ conv_b,
                                                      float* __restrict__ ws) {
  __shared__ float xin[48 * 129];
  __shared__ float rnorm[48];
  __shared__ float cwc[3 * 16 * 64];
  __shared__ float bnr1[256], bnr2[256];
  int tid = threadIdx.x;
  int bb = blockIdx.x >> 4, tcg = blockIdx.x & 15;
  const float* inp = inputs + ((size_t)bb * T_ + (size_t)tcg * 48) * D_;
  for (int idx = tid; idx < 48 * 128; idx += 256) {
    int r = idx >> 7, d = idx & 127;
    xin[r * 129 + d] = inp[idx];
  }
  __syncthreads();
  if (tid < 48) {
    float ss = 0.f;
    for (int d = 0; d < 128; ++d) { float v = xin[tid * 129 + d]; ss += v * v; }
    rnorm[tid] = 1.0f / fmaxf(sqrtf(ss), 1e-12f);
  }
  __syncthreads();
  for (int idx = tid; idx < 48 * 128; idx += 256) {
    int r = idx >> 7, d = idx & 127;
    xin[r * 129 + d] *= rnorm[r];
  }
  int e = tid & 63, tg = tid >> 6;
  float cb = conv_b[e];
  float acc[4];
#pragma unroll
  for (int q = 0; q < 4; ++q) acc[q] = cb;
  for (int ch = 0; ch < 8; ++ch) {
    __syncthreads();
    for (int idx = tid; idx < 3072; idx += 256) {
      int k = idx >> 10; int i2 = idx & 1023; int dd = i2 >> 6; int e2 = i2 & 63;
      cwc[idx] = ws[CWT_OFF + ((size_t)k * D_ + ch * 16 + dd) * E_ + e2];
    }
    __syncthreads();
    for (int dd = 0; dd < 16; ++dd) {
      int dcol = ch * 16 + dd;
#pragma unroll
      for (int k = 0; k < 3; ++k) {
        float w = cwc[(k * 16 + dd) * 64 + e];
#pragma unroll
        for (int q = 0; q < 4; ++q) {
          int tcl = tg * 4 + q;
          acc[q] += w * xin[(3 * tcl + k) * 129 + dcol];
        }
      }
    }
  }
  float ps = 0.f, pss = 0.f;
#pragma unroll
  for (int q = 0; q < 4; ++q) {
    int tcl = tg * 4 + q;
    ws[EMB_OFF + ((size_t)bb * TC_ + tcg * 16 + tcl) * E_ + e] = acc[q];
    ps += acc[q]; pss += acc[q] * acc[q];
  }
  bnr1[tg * 64 + e] = ps;
  bnr2[tg * 64 + e] = pss;
  __syncthreads();
  if (tid < 64) {
    float s1 = bnr1[tid] + bnr1[64 + tid] + bnr1[128 + tid] + bnr1[192 + tid];
    float s2 = bnr2[tid] + bnr2[64 + tid] + bnr2[128 + tid] + bnr2[192 + tid];
    atomicAdd(&ws[SUM_OFF + tid], s1);
    atomicAdd(&ws[SUM_OFF + 64 + tid], s2);
  }
}

// ---------------- BN finalize ----------------
__global__ void bn_finalize_kernel(const float* __restrict__ gamma,
                                   const float* __restrict__ beta,
                                   float* __restrict__ ws) {
  int e = threadIdx.x;
  if (e < 64) {
    const float n = (float)(B_ * TC_);
    float mean = ws[SUM_OFF + e] / n;
    float var = ws[SUM_OFF + 64 + e] / n - mean * mean;
    float sc = gamma[e] * rsqrtf(var + BNEPS);
    ws[SCL_OFF + e] = sc;
    ws[SCL_OFF + 64 + e] = beta[e] - mean * sc;
  }
}

// ---------------- z_x = relu(bn(emb)) @ w_ih^T + b_ih + b_hh ----------------
__global__ __launch_bounds__(256) void zx_kernel(const float* __restrict__ w_ih,
                                                 const float* __restrict__ b_ih,
                                                 const float* __restrict__ b_hh,
                                                 float* __restrict__ ws) {
  __shared__ __align__(16) float actT[16 * 64];
  int tid = threadIdx.x;
  int bb = blockIdx.x >> 4, tg2 = blockIdx.x & 15;
  for (int idx = tid; idx < 1024; idx += 256) {
    int tl = idx >> 6, e2 = idx & 63;
    float v = ws[EMB_OFF + ((size_t)bb * TC_ + tg2 * 16 + tl) * E_ + e2];
    actT[idx] = fmaxf(v * ws[SCL_OFF + e2] + ws[SCL_OFF + 64 + e2], 0.f);
  }
  __syncthreads();
  int j0 = tid, j1 = tid + 256;
  float acc0[16], acc1[16];
  float bias0 = b_ih[j0] + b_hh[j0];
  float bias1 = b_ih[j1] + b_hh[j1];
#pragma unroll
  for (int tl = 0; tl < 16; ++tl) { acc0[tl] = bias0; acc1[tl] = bias1; }
  for (int e4 = 0; e4 < 16; ++e4) {
    float4 w0 = *(const float4*)(w_ih + (size_t)j0 * 64 + e4 * 4);
    float4 w1 = *(const float4*)(w_ih + (size_t)j1 * 64 + e4 * 4);
#pragma unroll
    for (int tl = 0; tl < 16; ++tl) {
      float4 a4 = *(const float4*)(actT + tl * 64 + e4 * 4);
      acc0[tl] += w0.x * a4.x + w0.y * a4.y + w0.z * a4.z + w0.w * a4.w;
      acc1[tl] += w1.x * a4.x + w1.y * a4.y + w1.z * a4.z + w1.w * a4.w;
    }
  }
#pragma unroll
  for (int tl = 0; tl < 16; ++tl) {
    size_t base = ZX_OFF + ((size_t)bb * TC_ + tg2 * 16 + tl) * FH_;
    ws[base + j0] = acc0[tl];
    ws[base + j1] = acc1[tl];
  }
}

// ---------------- Gram tile helper (A-frags cached, each B-frag read once) ----------------
template <int NCT>
__device__ inline void gram_do(int rt, int ct0, int lane,
                               const __bf16* GtHi, const __bf16* GtLo,
                               float* M_s, float* y_s) {
  int m = lane & 15, q = lane >> 4;
  bf16x8 AH[4], AL[4];
#pragma unroll
  for (int kt = 0; kt < 4; ++kt) {
    AH[kt] = *(const bf16x8*)(GtHi + (rt * 16 + m) * 136 + kt * 32 + q * 8);
    AL[kt] = *(const bf16x8*)(GtLo + (rt * 16 + m) * 136 + kt * 32 + q * 8);
  }
  floatx4 C[NCT];
#pragma unroll
  for (int ci = 0; ci < NCT; ++ci) C[ci] = (floatx4){0.f, 0.f, 0.f, 0.f};
#pragma unroll
  for (int ci = 0; ci < NCT; ++ci) {
#pragma unroll
    for (int kt = 0; kt < 4; ++kt) {
      bf16x8 BH = *(const bf16x8*)(GtHi + ((ct0 + ci) * 16 + m) * 136 + kt * 32 + q * 8);
      bf16x8 BL = *(const bf16x8*)(GtLo + ((ct0 + ci) * 16 + m) * 136 + kt * 32 + q * 8);
      C[ci] = __builtin_amdgcn_mfma_f32_16x16x32_bf16(AH[kt], BH, C[ci], 0, 0, 0);
      C[ci] = __builtin_amdgcn_mfma_f32_16x16x32_bf16(AH[kt], BL, C[ci], 0, 0, 0);
      C[ci] = __builtin_amdgcn_mfma_f32_16x16x32_bf16(AL[kt], BH, C[ci], 0, 0, 0);
    }
  }
#pragma unroll
  for (int ci = 0; ci < NCT; ++ci) {
    int ct = ct0 + ci;
#pragma unroll
    for (int reg = 0; reg < 4; ++reg) {
      int grow = rt * 16 + q * 4 + reg;
      if (ct < 4) {
        int gcol = ct * 16 + m;
        M_s[grow * 65 + gcol] = EPSP * C[ci][reg] + ((grow == gcol) ? 1.f : 0.f);
      } else if (m == 0) {
        y_s[grow] = C[ci][reg];
      }
    }
  }
}

#define LD8(dst, base) { float4 _a = *(const float4*)(base); float4 _b = *(const float4*)((base) + 4); \
  dst[0]=_a.x; dst[1]=_a.y; dst[2]=_a.z; dst[3]=_a.w; dst[4]=_b.x; dst[5]=_b.y; dst[6]=_b.z; dst[7]=_b.w; }

union U4L { uint4 u; long l[2]; };

// ---------------- scan: 1 block/batch, 1024 threads (16 waves, 4 waves/SIMD) ----------------
// R5 left the machine latency-bound at 2 waves/SIMD (per-active-CU VALUBusy ~32%,
// step ~43k cy vs ~8k modeled). Double the in-block wave count: per-wave work in
// A/Gram/trailing halves, 4 waves/SIMD doubles latency hiding, and per-thread
// persistent state drops to ~64 VGPR (WH 32 + Wr 24 + gva 8) so the 128-VGPR
// budget holds with no spill. Serial Cholesky/solve (wave 0) unchanged — this
// round measures its true share: if scan stays >=4300us, round 7 rewrites it.
__global__ __launch_bounds__(1024)
void scan_kernel(const float* __restrict__ w_ih,
                 const float* __restrict__ lin_w,
                 const float* __restrict__ lin_b,
                 const float* __restrict__ ws,
                 float* __restrict__ out) {
  __shared__ __align__(16) __bf16 GtHi[80 * 136], GtLo[80 * 136]; // rows 0-63 G^T[e][h], 64 = s, 65-79 = 0
  __shared__ __align__(16) __bf16 hbH[128], hbL[128];             // h split bf16
  __shared__ __align__(8)  unsigned char hb8[128];                // h fp8 (x16)
  __shared__ float M_s[64 * 65];
  __shared__ float Lp_s[16 * 64];
  __shared__ __align__(16) float z0_s[512], zx_s[512];
  __shared__ __align__(16) float s_s[128], o_s[128], c_s[128], h_s[128];
  __shared__ float y_s[64];
  __shared__ __align__(8) float x_s[64];                          // solve result, f32
  __shared__ __align__(16) unsigned char W8L[4 * 1024 * 16];      // 64KB fp8-lo w_hh frags, [u4-slot][thread]

  const int tid = threadIdx.x;
  const int bb = blockIdx.x;
  const int lane = tid & 63;
  const int wv = tid >> 6;          // 0..15
  const int m = lane & 15, q = lane >> 4;
  const int h0 = wv * 8;            // B/E row group (16 waves x 8 rows)
  const int col = lane;             // B: G column (64 cols per wave-group, 1/thread)

  // ---- persistent: w_ih slice in f32 registers (exact; 24 VGPR) ----
  float Wr[3][8];
#pragma unroll
  for (int g = 0; g < 3; ++g) {
    const float* bse = w_ih + ((size_t)(g * 128 + h0)) * 64 + col;
#pragma unroll
    for (int r = 0; r < 8; ++r) Wr[g][r] = bse[(size_t)r * 64];
  }

  // ---- persistent: w_hh bf16-hi MFMA frags (8 x bf16x8 = 32 VGPRs) ----
  bf16x8 WH[2][4];
  {
    const uint4* whip = (const uint4*)(ws + WHIF_OFF) + (size_t)tid * 8;
#pragma unroll
    for (int rti = 0; rti < 2; ++rti)
#pragma unroll
      for (int kt = 0; kt < 4; ++kt) {
        uint4 t4 = whip[rti * 4 + kt];
        WH[rti][kt] = __builtin_bit_cast(bf16x8, t4);
      }
  }
  // ---- fp8-lo w_hh frags: global -> LDS once ([slot][thread] => conflict-free reads) ----
  {
    const uint4* src = (const uint4*)(ws + WLO8F_OFF) + (size_t)tid * 4;
    uint4* dst = (uint4*)W8L;
#pragma unroll
    for (int f = 0; f < 4; ++f) dst[f * 1024 + tid] = src[f];
  }
  // ---- zero-init ----
  for (int i = tid; i < 15 * 136; i += 1024) { GtHi[65 * 136 + i] = (__bf16)0.f; GtLo[65 * 136 + i] = (__bf16)0.f; }
  if (tid < 128) {
    c_s[tid] = 0.f; h_s[tid] = 0.f;
    hbH[tid] = (__bf16)0.f; hbL[tid] = (__bf16)0.f; hb8[tid] = 0;
  }
  const float* zxp = ws + ZX_OFF + (size_t)bb * TC_ * FH_;
  float dinv = 1.f;
  bf16x8 ZB;
#pragma unroll
  for (int j = 0; j < 8; ++j) ZB[j] = (__bf16)0.f;
  float zxcur = (tid < 512) ? zxp[tid] : 0.f;   // cross-step prefetch of z_x
  __syncthreads();

  for (int t = 0; t < TC_; ++t) {
    // ---- A: z = W_hh.h via MFMA (hi x (hh,hl) + fp8 lo x h8) ----
    {
      if (tid < 512) {
        zx_s[tid] = zxcur;
        if (t + 1 < TC_) zxcur = zxp[(size_t)(t + 1) * FH_ + tid];  // whole step to land
      }
      long B8[4];
#pragma unroll
      for (int kt = 0; kt < 4; ++kt)
        B8[kt] = (m == 0) ? *(const long*)(hb8 + kt * 32 + q * 8) : 0L;
      floatx4 C[2];
      // fp8-lo correction: frags from LDS (lane-consecutive 16B, conflict-free)
      {
        U4L wa[4];
#pragma unroll
        for (int i = 0; i < 4; ++i) wa[i].u = ((const uint4*)W8L)[i * 1024 + tid];
#pragma unroll
        for (int rti = 0; rti < 2; ++rti) {
          floatx4 C8 = {0, 0, 0, 0};
#pragma unroll
          for (int kt = 0; kt < 4; ++kt) {
            long A0 = wa[(rti * 4 + kt) >> 1].l[kt & 1];
            C8 = __builtin_amdgcn_mfma_f32_16x16x32_fp8_fp8(A0, B8[kt], C8, 0, 0, 0);
          }
          C[rti] = C8 * S18;
        }
      }
      // bf16-hi x (hh + hl)
#pragma unroll
      for (int p = 0; p < 2; ++p) {
        const __bf16* hb = p ? hbL : hbH;
#pragma unroll
        for (int kt = 0; kt < 4; ++kt) {
          bf16x8 Bf = (m == 0) ? *(const bf16x8*)(hb + kt * 32 + q * 8) : ZB;
#pragma unroll
          for (int rti = 0; rti < 2; ++rti)
            C[rti] = __builtin_amdgcn_mfma_f32_16x16x32_bf16(WH[rti][kt], Bf, C[rti], 0, 0, 0);
        }
      }
      if (m == 0) {
#pragma unroll
        for (int rti = 0; rti < 2; ++rti)
          *(floatx4*)(z0_s + wv * 32 + rti * 16 + q * 4) = C[rti];
      }
    }
    __syncthreads();
    // ---- B: gates (redundant x64) + G build from register w_ih ----
    float gva[8];   // exact f32 G for this thread's (h0..h0+7) x col; used again in E
    {
      float zA[8], xA[8], zi[8], zf[8], zg[8], zo[8], cc[8];
      LD8(zA, z0_s + h0) LD8(xA, zx_s + h0)
#pragma unroll
      for (int r = 0; r < 8; ++r) zi[r] = zA[r] + xA[r];
      LD8(zA, z0_s + 128 + h0) LD8(xA, zx_s + 128 + h0)
#pragma unroll
      for (int r = 0; r < 8; ++r) zf[r] = zA[r] + xA[r];
      LD8(zA, z0_s + 256 + h0) LD8(xA, zx_s + 256 + h0)
#pragma unroll
      for (int r = 0; r < 8; ++r) zg[r] = zA[r] + xA[r];
      LD8(zA, z0_s + 384 + h0) LD8(xA, zx_s + 384 + h0)
#pragma unroll
      for (int r = 0; r < 8; ++r) zo[r] = zA[r] + xA[r];
      LD8(cc, c_s + h0)
      float a1[8], a2[8], a3[8], sv[8], ov[8];
#pragma unroll
      for (int r = 0; r < 8; ++r) {
        float ig = fsigmoid(zi[r]);
        float fg = fsigmoid(zf[r]);
        float gg = ftanh(zg[r]);
        sv[r] = fg * cc[r] + ig * gg;
        ov[r] = fsigmoid(zo[r]);
        a1[r] = ig * (1.f - ig) * gg;
        a2[r] = fg * (1.f - fg) * cc[r];
        a3[r] = ig * (1.f - gg * gg);
      }
      if (lane == 0) {
        *(float4*)(s_s + h0)     = (float4){sv[0], sv[1], sv[2], sv[3]};
        *(float4*)(s_s + h0 + 4) = (float4){sv[4], sv[5], sv[6], sv[7]};
        *(float4*)(o_s + h0)     = (float4){ov[0], ov[1], ov[2], ov[3]};
        *(float4*)(o_s + h0 + 4) = (float4){ov[4], ov[5], ov[6], ov[7]};
        bf16x8 sh, sl;
#pragma unroll
        for (int r = 0; r < 8; ++r) {
          __bf16 hi = (__bf16)sv[r];
          sh[r] = hi; sl[r] = (__bf16)(sv[r] - (float)hi);
        }
        *(bf16x8*)(GtHi + 64 * 136 + h0) = sh;
        *(bf16x8*)(GtLo + 64 * 136 + h0) = sl;
      }
      {
        bf16x8 gh, gl;
#pragma unroll
        for (int r = 0; r < 8; ++r) {
          float gv = a1[r] * Wr[0][r] + a2[r] * Wr[1][r] + a3[r] * Wr[2][r];
          gva[r] = gv;
          __bf16 hi = (__bf16)gv;
          gh[r] = hi; gl[r] = (__bf16)(gv - (float)hi);
        }
        *(bf16x8*)(GtHi + col * 136 + h0) = gh;
        *(bf16x8*)(GtLo + col * 136 + h0) = gl;
      }
    }
    __syncthreads();
    // ---- Gram via MFMA: M = I + eps*G^T G ; y = G^T s (16 waves: rt = wv&3, cs = wv>>2) ----
    {
      int rt = wv & 3, cs = wv >> 2;
      if (cs < 3) gram_do<1>(rt, cs, lane, GtHi, GtLo, M_s, y_s);
      else        gram_do<2>(rt, 3, lane, GtHi, GtLo, M_s, y_s);
    }
    __syncthreads();
    // ---- Cholesky (panel-16, readlane pivots; proven) ----
#pragma unroll 1
    for (int pan = 0; pan < 4; ++pan) {
      int j0 = pan * 16;
      if (tid < 64) {
        float p[16];
#pragma unroll
        for (int jj = 0; jj < 16; ++jj) p[jj] = M_s[lane * 65 + j0 + jj];
#pragma unroll
        for (int jj = 0; jj < 16; ++jj) {
          float d  = rl(p[jj], j0 + jj);
          float rs = frsq(d);
          p[jj] *= rs;
          dinv = (lane == j0 + jj) ? rs : dinv;
#pragma unroll
          for (int kk = jj + 1; kk < 16; ++kk) {
            float l = rl(p[jj], j0 + kk);
            p[kk] -= p[jj] * l;
          }
        }
#pragma unroll
        for (int jj = 0; jj < 16; ++jj) {
          M_s[lane * 65 + j0 + jj] = p[jj];
          Lp_s[jj * 64 + lane] = p[jj];
        }
        if (pan == 3) {
          float r = y_s[lane];
#pragma unroll 16
          for (int i = 0; i < 64; ++i) {
            float Lri = M_s[lane * 65 + i];
            float vv  = rl(r, i) * rl(dinv, i);
            float upd = r - Lri * vv;
            r = (lane == i) ? vv : ((lane > i) ? upd : r);
          }
#pragma unroll 16
          for (int i = 63; i >= 0; --i) {
            float Lil = M_s[i * 65 + lane];
            float vv  = rl(r, i) * rl(dinv, i);
            float upd = r - Lil * vv;
            r = (lane == i) ? vv : ((lane < i) ? upd : r);
          }
          x_s[lane] = r;
        }
      }
      __syncthreads();
      if (pan < 3) {
        float Lrow[16];
#pragma unroll
        for (int jj = 0; jj < 16; ++jj) Lrow[jj] = Lp_s[jj * 64 + lane];
        for (int k = j0 + 16 + wv; k < 64; k += 16) {
          float acc = M_s[lane * 65 + k];
#pragma unroll
          for (int jj = 0; jj < 16; ++jj) acc -= Lrow[jj] * Lp_s[jj * 64 + k];
          M_s[lane * 65 + k] = acc;
        }
        __syncthreads();
      }
    }
    // ---- E: u = G x from register G + 64-lane butterfly reduce; c,h update ----
    {
      float xl = x_s[col];
      float u0[8];
#pragma unroll
      for (int r = 0; r < 8; ++r) u0[r] = gva[r] * xl;
#pragma unroll
      for (int sft = 1; sft < 64; sft <<= 1)
#pragma unroll
        for (int r = 0; r < 8; ++r) u0[r] += __shfl_xor(u0[r], sft, 64);
      if (lane == 0) {
        float cn[8], hn[8];
        bf16x8 hh8, hl8;
        unsigned long long h8v = 0ULL;
#pragma unroll
        for (int r = 0; r < 8; ++r) {
          cn[r] = s_s[h0 + r] - EPSP * u0[r];
          hn[r] = o_s[h0 + r] * ftanh(cn[r]);
          __bf16 hi = (__bf16)hn[r];
          hh8[r] = hi; hl8[r] = (__bf16)(hn[r] - (float)hi);
          h8v |= ((unsigned long long)enc8(hn[r] * 16.f)) << (8 * r);
        }
        *(float4*)(c_s + h0)     = (float4){cn[0], cn[1], cn[2], cn[3]};
        *(float4*)(c_s + h0 + 4) = (float4){cn[4], cn[5], cn[6], cn[7]};
        *(float4*)(h_s + h0)     = (float4){hn[0], hn[1], hn[2], hn[3]};
        *(float4*)(h_s + h0 + 4) = (float4){hn[4], hn[5], hn[6], hn[7]};
        *(bf16x8*)(hbH + h0) = hh8;
        *(bf16x8*)(hbL + h0) = hl8;
        *(unsigned long long*)(hb8 + h0) = h8v;
      }
    }
    __syncthreads();
  }
  // ---- head ----
  if (tid < O_) {
    float acc = lin_b[tid];
    for (int hh2 = 0; hh2 < 128; ++hh2) acc += h_s[hh2] * lin_w[tid * 128 + hh2];
    out[(size_t)bb * O_ + tid] = acc;
  }
}

// ---------------- launch ----------------
extern "C" void kernel_launch(void* const* d_in, const int* in_sizes, int n_in,
                              void* d_out, int out_size, void* d_ws, size_t ws_size,
                              hipStream_t stream) {
  (void)in_sizes; (void)n_in; (void)out_size;
  const float* inputs  = (const float*)d_in[0];
  const float* conv_w  = (const float*)d_in[2];
  const float* conv_b  = (const float*)d_in[3];
  const float* gamma   = (const float*)d_in[4];
  const float* beta    = (const float*)d_in[5];
  const float* w_ih    = (const float*)d_in[6];
  const float* w_hh    = (const float*)d_in[7];
  const float* b_ih    = (const float*)d_in[8];
  const float* b_hh    = (const float*)d_in[9];
  const float* lin_w   = (const float*)d_in[10];
  const float* lin_b   = (const float*)d_in[11];
  float* out = (float*)d_out;
  float* ws  = (float*)d_ws;

  if (ws_size < WS_FLOATS * sizeof(float)) return;

  hipLaunchKernelGGL(prep_kernel, dim3(192), dim3(256), 0, stream, conv_w, w_hh, ws);
  hipLaunchKernelGGL(conv_bn_kernel, dim3(1024), dim3(256), 0, stream, inputs, conv_b, ws);
  hipLaunchKernelGGL(bn_finalize_kernel, dim3(1), dim3(64), 0, stream, gamma, beta, ws);
  hipLaunchKernelGGL(zx_kernel, dim3(1024), dim3(256), 0, stream, w_ih, b_ih, b_hh, ws);
  hipLaunchKernelGGL(scan_kernel, dim3(64), dim3(1024), 0, stream, w_ih, lin_w, lin_b, ws, out);
}

// Round 9
// 4631.715 us; speedup vs baseline: 1.4111x; 1.4111x over previous
//
#include <hip/hip_runtime.h>
#include <math.h>

// ---------------- problem constants ----------------
#define EPSP 5.0f
#define BNEPS 1e-5f
constexpr int B_  = 64;    // batch
constexpr int T_  = 768;   // timesteps in
constexpr int D_  = 128;   // input feature
constexpr int E_  = 64;    // embedding (conv out channels)
constexpr int H_  = 128;   // hidden
constexpr int FH_ = 512;   // 4*H
constexpr int TC_ = 256;   // conv output steps
constexpr int O_  = 10;    // output classes

// ---------------- workspace layout (floats) ----------------
constexpr size_t EMB_OFF   = 0;                                  // B*TC*E
constexpr size_t SUM_OFF   = EMB_OFF + (size_t)B_ * TC_ * E_;    // 128
constexpr size_t SCL_OFF   = SUM_OFF + 128;                      // 128
constexpr size_t CWT_OFF   = SCL_OFF + 128;                      // 24576 [k][d][e]
constexpr size_t WHIF_OFF  = CWT_OFF + (size_t)E_ * D_ * 3;      // 32768: w_hh bf16-hi MFMA frags, per-thread (512-thr layout)
constexpr size_t WLO8F_OFF = WHIF_OFF + 32768;                   // 16384: w_hh fp8-lo (x2^14) frags, per-thread
constexpr size_t WTHI_OFF  = WLO8F_OFF + 16384;                  // unused gap
constexpr size_t WTLO8_OFF = WTHI_OFF + 12288;                   // unused gap
constexpr size_t ZX_OFF    = WTLO8_OFF + 6144;                   // B*TC*FH
constexpr size_t WS_FLOATS = ZX_OFF + (size_t)B_ * TC_ * FH_;    // < proven 9,560,320 capacity

typedef __bf16 bf16x8 __attribute__((ext_vector_type(8)));
typedef float  floatx4 __attribute__((ext_vector_type(4)));

__device__ inline float fast_rcp(float x) { return __builtin_amdgcn_rcpf(x); }
__device__ inline float frsq(float x) { return __builtin_amdgcn_rsqf(x); }
__device__ inline float fexp2(float x) { return __builtin_amdgcn_exp2f(x); }
__device__ inline float rl(float v, int lane) {
  return __int_as_float(__builtin_amdgcn_readlane(__float_as_int(v), lane));
}
#define LOG2E 1.4426950408889634f
__device__ inline float fsigmoid(float x) { return fast_rcp(1.f + fexp2(-LOG2E * x)); }
__device__ inline float ftanh(float x) { return 1.f - 2.f * fast_rcp(1.f + fexp2(2.f * LOG2E * x)); }

// fp8 e4m3fn encode (truncating, flush-to-zero below 2^-6). Values pre-scaled to normal range.
__device__ inline unsigned char enc8(float v) {
  unsigned b = __float_as_uint(v);
  unsigned s = b >> 31;
  int e = (int)((b >> 23) & 0xFF) - 127;
  if (e < -6) return 0;
  unsigned m3 = (b >> 20) & 7;
  return (unsigned char)((s << 7) | ((unsigned)(e + 7) << 3) | m3);
}
#define S18 3.814697265625e-06f     // 2^-18

// ---------------- prep: weight repack (w_hh frags + conv image) ----------------
// 512-thread scan layout: thread st (0..511), frag f=(rti,kt) f<16, byte j
__global__ void prep_kernel(const float* __restrict__ conv_w,
                            const float* __restrict__ w_hh,
                            float* __restrict__ ws) {
  int gid = blockIdx.x * blockDim.x + threadIdx.x;
  int nthr = gridDim.x * blockDim.x;
  for (int i = gid; i < 128; i += nthr) ws[SUM_OFF + i] = 0.f;
  __bf16* whiF = (__bf16*)(ws + WHIF_OFF);
  unsigned char* wlo8F = (unsigned char*)(ws + WLO8F_OFF);
  for (int s = gid; s < 512 * 128; s += nthr) {
    int st = s >> 7, r2 = s & 127, f = r2 >> 3, j = r2 & 7;
    int wv = st >> 6, lane = st & 63, m = lane & 15, q = lane >> 4;
    int rti = f >> 2, kt = f & 3;
    int R = wv * 64 + rti * 16 + m;
    int k = kt * 32 + q * 8 + j;
    float w = w_hh[(size_t)R * 128 + k];
    __bf16 hi = (__bf16)w;
    whiF[s] = hi;
    wlo8F[s] = enc8((w - (float)hi) * 16384.f);
  }
  // conv_w [e][d][k] -> [k][d][e]
  for (int s = gid; s < E_ * D_ * 3; s += nthr) {
    int e = s / 384; int r = s - e * 384; int d = r / 3; int k = r - d * 3;
    ws[CWT_OFF + ((size_t)k * D_ + d) * E_ + e] = conv_w[s];
  }
}

// ---------------- conv + L2-normalize + BN partial sums ----------------
__global__ __launch_bounds__(256) void conv_bn_kernel(const float* __restrict__ inputs,
                                                      const float* __restrict__ conv_b,
                                                      float* __restrict__ ws) {
  __shared__ float xin[48 * 129];
  __shared__ float rnorm[48];
  __shared__ float cwc[3 * 16 * 64];
  __shared__ float bnr1[256], bnr2[256];
  int tid = threadIdx.x;
  int bb = blockIdx.x >> 4, tcg = blockIdx.x & 15;
  const float* inp = inputs + ((size_t)bb * T_ + (size_t)tcg * 48) * D_;
  for (int idx = tid; idx < 48 * 128; idx += 256) {
    int r = idx >> 7, d = idx & 127;
    xin[r * 129 + d] = inp[idx];
  }
  __syncthreads();
  if (tid < 48) {
    float ss = 0.f;
    for (int d = 0; d < 128; ++d) { float v = xin[tid * 129 + d]; ss += v * v; }
    rnorm[tid] = 1.0f / fmaxf(sqrtf(ss), 1e-12f);
  }
  __syncthreads();
  for (int idx = tid; idx < 48 * 128; idx += 256) {
    int r = idx >> 7, d = idx & 127;
    xin[r * 129 + d] *= rnorm[r];
  }
  int e = tid & 63, tg = tid >> 6;
  float cb = conv_b[e];
  float acc[4];
#pragma unroll
  for (int q = 0; q < 4; ++q) acc[q] = cb;
  for (int ch = 0; ch < 8; ++ch) {
    __syncthreads();
    for (int idx = tid; idx < 3072; idx += 256) {
      int k = idx >> 10; int i2 = idx & 1023; int dd = i2 >> 6; int e2 = i2 & 63;
      cwc[idx] = ws[CWT_OFF + ((size_t)k * D_ + ch * 16 + dd) * E_ + e2];
    }
    __syncthreads();
    for (int dd = 0; dd < 16; ++dd) {
      int dcol = ch * 16 + dd;
#pragma unroll
      for (int k = 0; k < 3; ++k) {
        float w = cwc[(k * 16 + dd) * 64 + e];
#pragma unroll
        for (int q = 0; q < 4; ++q) {
          int tcl = tg * 4 + q;
          acc[q] += w * xin[(3 * tcl + k) * 129 + dcol];
        }
      }
    }
  }
  float ps = 0.f, pss = 0.f;
#pragma unroll
  for (int q = 0; q < 4; ++q) {
    int tcl = tg * 4 + q;
    ws[EMB_OFF + ((size_t)bb * TC_ + tcg * 16 + tcl) * E_ + e] = acc[q];
    ps += acc[q]; pss += acc[q] * acc[q];
  }
  bnr1[tg * 64 + e] = ps;
  bnr2[tg * 64 + e] = pss;
  __syncthreads();
  if (tid < 64) {
    float s1 = bnr1[tid] + bnr1[64 + tid] + bnr1[128 + tid] + bnr1[192 + tid];
    float s2 = bnr2[tid] + bnr2[64 + tid] + bnr2[128 + tid] + bnr2[192 + tid];
    atomicAdd(&ws[SUM_OFF + tid], s1);
    atomicAdd(&ws[SUM_OFF + 64 + tid], s2);
  }
}

// ---------------- BN finalize ----------------
__global__ void bn_finalize_kernel(const float* __restrict__ gamma,
                                   const float* __restrict__ beta,
                                   float* __restrict__ ws) {
  int e = threadIdx.x;
  if (e < 64) {
    const float n = (float)(B_ * TC_);
    float mean = ws[SUM_OFF + e] / n;
    float var = ws[SUM_OFF + 64 + e] / n - mean * mean;
    float sc = gamma[e] * rsqrtf(var + BNEPS);
    ws[SCL_OFF + e] = sc;
    ws[SCL_OFF + 64 + e] = beta[e] - mean * sc;
  }
}

// ---------------- z_x = relu(bn(emb)) @ w_ih^T + b_ih + b_hh ----------------
__global__ __launch_bounds__(256) void zx_kernel(const float* __restrict__ w_ih,
                                                 const float* __restrict__ b_ih,
                                                 const float* __restrict__ b_hh,
                                                 float* __restrict__ ws) {
  __shared__ __align__(16) float actT[16 * 64];
  int tid = threadIdx.x;
  int bb = blockIdx.x >> 4, tg2 = blockIdx.x & 15;
  for (int idx = tid; idx < 1024; idx += 256) {
    int tl = idx >> 6, e2 = idx & 63;
    float v = ws[EMB_OFF + ((size_t)bb * TC_ + tg2 * 16 + tl) * E_ + e2];
    actT[idx] = fmaxf(v * ws[SCL_OFF + e2] + ws[SCL_OFF + 64 + e2], 0.f);
  }
  __syncthreads();
  int j0 = tid, j1 = tid + 256;
  float acc0[16], acc1[16];
  float bias0 = b_ih[j0] + b_hh[j0];
  float bias1 = b_ih[j1] + b_hh[j1];
#pragma unroll
  for (int tl = 0; tl < 16; ++tl) { acc0[tl] = bias0; acc1[tl] = bias1; }
  for (int e4 = 0; e4 < 16; ++e4) {
    float4 w0 = *(const float4*)(w_ih + (size_t)j0 * 64 + e4 * 4);
    float4 w1 = *(const float4*)(w_ih + (size_t)j1 * 64 + e4 * 4);
#pragma unroll
    for (int tl = 0; tl < 16; ++tl) {
      float4 a4 = *(const float4*)(actT + tl * 64 + e4 * 4);
      acc0[tl] += w0.x * a4.x + w0.y * a4.y + w0.z * a4.z + w0.w * a4.w;
      acc1[tl] += w1.x * a4.x + w1.y * a4.y + w1.z * a4.z + w1.w * a4.w;
    }
  }
#pragma unroll
  for (int tl = 0; tl < 16; ++tl) {
    size_t base = ZX_OFF + ((size_t)bb * TC_ + tg2 * 16 + tl) * FH_;
    ws[base + j0] = acc0[tl];
    ws[base + j1] = acc1[tl];
  }
}

// ---------------- Gram tile helper (A-frags cached, each B-frag read once) ----------------
template <int NCT>
__device__ inline void gram_do(int rt, int ct0, int lane,
                               const __bf16* GtHi, const __bf16* GtLo,
                               float* M_s, float* y_s) {
  int m = lane & 15, q = lane >> 4;
  bf16x8 AH[4], AL[4];
#pragma unroll
  for (int kt = 0; kt < 4; ++kt) {
    AH[kt] = *(const bf16x8*)(GtHi + (rt * 16 + m) * 136 + kt * 32 + q * 8);
    AL[kt] = *(const bf16x8*)(GtLo + (rt * 16 + m) * 136 + kt * 32 + q * 8);
  }
  floatx4 C[NCT];
#pragma unroll
  for (int ci = 0; ci < NCT; ++ci) C[ci] = (floatx4){0.f, 0.f, 0.f, 0.f};
#pragma unroll
  for (int ci = 0; ci < NCT; ++ci) {
#pragma unroll
    for (int kt = 0; kt < 4; ++kt) {
      bf16x8 BH = *(const bf16x8*)(GtHi + ((ct0 + ci) * 16 + m) * 136 + kt * 32 + q * 8);
      bf16x8 BL = *(const bf16x8*)(GtLo + ((ct0 + ci) * 16 + m) * 136 + kt * 32 + q * 8);
      C[ci] = __builtin_amdgcn_mfma_f32_16x16x32_bf16(AH[kt], BH, C[ci], 0, 0, 0);
      C[ci] = __builtin_amdgcn_mfma_f32_16x16x32_bf16(AH[kt], BL, C[ci], 0, 0, 0);
      C[ci] = __builtin_amdgcn_mfma_f32_16x16x32_bf16(AL[kt], BH, C[ci], 0, 0, 0);
    }
  }
#pragma unroll
  for (int ci = 0; ci < NCT; ++ci) {
    int ct = ct0 + ci;
#pragma unroll
    for (int reg = 0; reg < 4; ++reg) {
      int grow = rt * 16 + q * 4 + reg;
      if (ct < 4) {
        int gcol = ct * 16 + m;
        M_s[grow * 65 + gcol] = EPSP * C[ci][reg] + ((grow == gcol) ? 1.f : 0.f);
      } else if (m == 0) {
        y_s[grow] = C[ci][reg];
      }
    }
  }
}

#define LD8(dst, base) { float4 _a = *(const float4*)(base); float4 _b = *(const float4*)((base) + 4); \
  dst[0]=_a.x; dst[1]=_a.y; dst[2]=_a.z; dst[3]=_a.w; dst[4]=_b.x; dst[5]=_b.y; dst[6]=_b.z; dst[7]=_b.w; }

union U4L { uint4 u; long l[2]; };

// ---------------- scan: 1 block/batch, 512 threads (R5 base + R7 Cholesky rewrite) ----------------
// R6 showed 1024 threads regress (+23%): barriers cost more, serial fraction grows,
// allocator re-spills. Revert to R5. R7 changes (Cholesky subsystem only):
//  (a) factor stores A = L*D^-1, strict-lower, zeros elsewhere -> solves become
//      maskless rl+fma chains (forward col-oriented, tau = dinv^2*r, backward
//      row-oriented in tau-space; x = tau, no final scale). ~2x shorter serial chain.
//  (b) lookahead: factor(p) on wave 0 runs concurrently with waves 1-7 applying
//      panel p-1's trailing to columns beyond the next panel (disjoint cols,
//      double-buffered Lp panels). Hides factor(1)/factor(2).
__global__ __launch_bounds__(512, 2)
void scan_kernel(const float* __restrict__ w_ih,
                 const float* __restrict__ lin_w,
                 const float* __restrict__ lin_b,
                 const float* __restrict__ ws,
                 float* __restrict__ out) {
  __shared__ __align__(16) __bf16 GtHi[80 * 136], GtLo[80 * 136]; // rows 0-63 G^T[e][h], 64 = s, 65-79 = 0
  __shared__ __align__(16) __bf16 hbH[128], hbL[128];             // h split bf16
  __shared__ __align__(8)  unsigned char hb8[128];                // h fp8 (x16)
  __shared__ float M_s[64 * 65];
  __shared__ float Lp2_s[2 * 16 * 64];                            // double-buffered panel L (raw)
  __shared__ __align__(16) float z0_s[512], zx_s[512];
  __shared__ __align__(16) float s_s[128], o_s[128], c_s[128], h_s[128];
  __shared__ float y_s[64];
  __shared__ __align__(8) float x_s[64];                          // solve result, f32
  __shared__ __align__(16) unsigned char W8L[512 * 128];          // 64KB fp8-lo w_hh frags, [frag f][thread]x16B

  const int tid = threadIdx.x;
  const int bb = blockIdx.x;
  const int lane = tid & 63;
  const int wv = tid >> 6;          // 0..7
  const int m = lane & 15, q = lane >> 4;
  const int hg = tid >> 5;          // 0..15 (G-build: 8 rows)
  const int ep = tid & 31;          // 0..31 (G-build: 2 cols)
  const int h0 = hg * 8, e0 = ep * 2;

  // ---- persistent: w_ih slice in f32 registers (exact; loaded once from L2) ----
  float Wr[3][2][8];
#pragma unroll
  for (int g = 0; g < 3; ++g)
#pragma unroll
    for (int e = 0; e < 2; ++e) {
      const float* bse = w_ih + ((size_t)(g * 128 + h0)) * 64 + e0 + e;
#pragma unroll
      for (int r = 0; r < 8; ++r) Wr[g][e][r] = bse[(size_t)r * 64];
    }

  // ---- persistent: w_hh bf16-hi MFMA frags (16 x bf16x8 = 64 VGPRs) ----
  bf16x8 WH[4][4];
  {
    const uint4* whip = (const uint4*)(ws + WHIF_OFF) + (size_t)tid * 16;
#pragma unroll
    for (int rti = 0; rti < 4; ++rti)
#pragma unroll
      for (int kt = 0; kt < 4; ++kt) {
        uint4 t4 = whip[rti * 4 + kt];
        WH[rti][kt] = __builtin_bit_cast(bf16x8, t4);
      }
  }
  // ---- fp8-lo w_hh frags: global -> LDS once ([frag][thread] => conflict-free reads) ----
  {
    const uint4* src = (const uint4*)(ws + WLO8F_OFF) + (size_t)tid * 8;
    uint4* dst = (uint4*)W8L;
#pragma unroll
    for (int f = 0; f < 8; ++f) dst[f * 512 + tid] = src[f];
  }
  // ---- zero-init ----
  for (int i = tid; i < 15 * 136; i += 512) { GtHi[65 * 136 + i] = (__bf16)0.f; GtLo[65 * 136 + i] = (__bf16)0.f; }
  if (tid < 128) {
    c_s[tid] = 0.f; h_s[tid] = 0.f;
    hbH[tid] = (__bf16)0.f; hbL[tid] = (__bf16)0.f; hb8[tid] = 0;
  }
  const float* zxp = ws + ZX_OFF + (size_t)bb * TC_ * FH_;
  float dinv = 1.f;
  bf16x8 ZB;
#pragma unroll
  for (int j = 0; j < 8; ++j) ZB[j] = (__bf16)0.f;
  float zxcur = zxp[tid];               // cross-step prefetch of z_x
  __syncthreads();

  for (int t = 0; t < TC_; ++t) {
    // ---- A: z = W_hh.h via MFMA (hi x (hh,hl) + fp8 lo x h8) ----
    {
      zx_s[tid] = zxcur;
      if (t + 1 < TC_) zxcur = zxp[(size_t)(t + 1) * FH_ + tid];  // whole step to land
      long B8[4];
#pragma unroll
      for (int kt = 0; kt < 4; ++kt)
        B8[kt] = (m == 0) ? *(const long*)(hb8 + kt * 32 + q * 8) : 0L;
      floatx4 C[4];
      // fp8-lo correction: frags from LDS (lane-consecutive 16B, conflict-free)
#pragma unroll
      for (int h2 = 0; h2 < 2; ++h2) {
        U4L wa[4];
#pragma unroll
        for (int i = 0; i < 4; ++i) wa[i].u = ((const uint4*)W8L)[(h2 * 4 + i) * 512 + tid];
        floatx4 C8a = {0,0,0,0}, C8b = {0,0,0,0};
#pragma unroll
        for (int kt = 0; kt < 4; ++kt) {
          long A0 = wa[(0 * 4 + kt) >> 1].l[kt & 1];
          long A1 = wa[(1 * 4 + kt) >> 1].l[kt & 1];
          C8a = __builtin_amdgcn_mfma_f32_16x16x32_fp8_fp8(A0, B8[kt], C8a, 0, 0, 0);
          C8b = __builtin_amdgcn_mfma_f32_16x16x32_fp8_fp8(A1, B8[kt], C8b, 0, 0, 0);
        }
        C[h2 * 2 + 0] = C8a * S18;
        C[h2 * 2 + 1] = C8b * S18;
      }
      // bf16-hi x (hh + hl)
#pragma unroll
      for (int p = 0; p < 2; ++p) {
        const __bf16* hb = p ? hbL : hbH;
#pragma unroll
        for (int kt = 0; kt < 4; ++kt) {
          bf16x8 Bf = (m == 0) ? *(const bf16x8*)(hb + kt * 32 + q * 8) : ZB;
#pragma unroll
          for (int rti = 0; rti < 4; ++rti)
            C[rti] = __builtin_amdgcn_mfma_f32_16x16x32_bf16(WH[rti][kt], Bf, C[rti], 0, 0, 0);
        }
      }
      if (m == 0) {
#pragma unroll
        for (int rti = 0; rti < 4; ++rti)
          *(floatx4*)(z0_s + wv * 64 + rti * 16 + q * 4) = C[rti];
      }
    }
    __syncthreads();
    // ---- B: gates (redundant x32) + G build from register w_ih ----
    float gva[2][8];   // exact f32 G for this thread's (h0..h0+7) x (e0,e0+1); used again in E
    {
      float zA[8], xA[8], zi[8], zf[8], zg[8], zo[8], cc[8];
      LD8(zA, z0_s + h0) LD8(xA, zx_s + h0)
#pragma unroll
      for (int r = 0; r < 8; ++r) zi[r] = zA[r] + xA[r];
      LD8(zA, z0_s + 128 + h0) LD8(xA, zx_s + 128 + h0)
#pragma unroll
      for (int r = 0; r < 8; ++r) zf[r] = zA[r] + xA[r];
      LD8(zA, z0_s + 256 + h0) LD8(xA, zx_s + 256 + h0)
#pragma unroll
      for (int r = 0; r < 8; ++r) zg[r] = zA[r] + xA[r];
      LD8(zA, z0_s + 384 + h0) LD8(xA, zx_s + 384 + h0)
#pragma unroll
      for (int r = 0; r < 8; ++r) zo[r] = zA[r] + xA[r];
      LD8(cc, c_s + h0)
      float a1[8], a2[8], a3[8], sv[8], ov[8];
#pragma unroll
      for (int r = 0; r < 8; ++r) {
        float ig = fsigmoid(zi[r]);
        float fg = fsigmoid(zf[r]);
        float gg = ftanh(zg[r]);
        sv[r] = fg * cc[r] + ig * gg;
        ov[r] = fsigmoid(zo[r]);
        a1[r] = ig * (1.f - ig) * gg;
        a2[r] = fg * (1.f - fg) * cc[r];
        a3[r] = ig * (1.f - gg * gg);
      }
      if (ep == 0) {
        *(float4*)(s_s + h0)     = (float4){sv[0], sv[1], sv[2], sv[3]};
        *(float4*)(s_s + h0 + 4) = (float4){sv[4], sv[5], sv[6], sv[7]};
        *(float4*)(o_s + h0)     = (float4){ov[0], ov[1], ov[2], ov[3]};
        *(float4*)(o_s + h0 + 4) = (float4){ov[4], ov[5], ov[6], ov[7]};
        bf16x8 sh, sl;
#pragma unroll
        for (int r = 0; r < 8; ++r) {
          __bf16 hi = (__bf16)sv[r];
          sh[r] = hi; sl[r] = (__bf16)(sv[r] - (float)hi);
        }
        *(bf16x8*)(GtHi + 64 * 136 + h0) = sh;
        *(bf16x8*)(GtLo + 64 * 136 + h0) = sl;
      }
#pragma unroll
      for (int e = 0; e < 2; ++e) {
        int col = e0 + e;
        bf16x8 gh, gl;
#pragma unroll
        for (int r = 0; r < 8; ++r) {
          float gv = a1[r] * Wr[0][e][r] + a2[r] * Wr[1][e][r] + a3[r] * Wr[2][e][r];
          gva[e][r] = gv;
          __bf16 hi = (__bf16)gv;
          gh[r] = hi; gl[r] = (__bf16)(gv - (float)hi);
        }
        *(bf16x8*)(GtHi + col * 136 + h0) = gh;
        *(bf16x8*)(GtLo + col * 136 + h0) = gl;
      }
    }
    __syncthreads();
    // ---- Gram via MFMA: M = I + eps*G^T G ; y = G^T s ----
    if (wv < 4) gram_do<3>(wv, 0, lane, GtHi, GtLo, M_s, y_s);
    else        gram_do<2>(wv - 4, 3, lane, GtHi, GtLo, M_s, y_s);
    __syncthreads();
    // ---- Cholesky: lookahead schedule + scaled-store (R7) ----
#pragma unroll 1
    for (int pan = 0; pan < 4; ++pan) {
      int j0 = pan * 16;
      float* Lpw = Lp2_s + (pan & 1) * (16 * 64);          // factor(pan) writes (raw L)
      float* Lpr = Lp2_s + (((pan & 1) ^ 1)) * (16 * 64);  // trailRest reads panel pan-1
      if (tid < 64) {
        // factor(pan): wave 0; stores raw L to Lpw, scaled A=L*D^-1 (strict-lower) to M_s
        float p[16];
#pragma unroll
        for (int jj = 0; jj < 16; ++jj) p[jj] = M_s[lane * 65 + j0 + jj];
#pragma unroll
        for (int jj = 0; jj < 16; ++jj) {
          float d  = rl(p[jj], j0 + jj);
          float rs = frsq(d);
          p[jj] *= rs;
          dinv = (lane == j0 + jj) ? rs : dinv;
          M_s[lane * 65 + j0 + jj] = (lane > j0 + jj) ? p[jj] * rs : 0.f;
          Lpw[jj * 64 + lane] = p[jj];
#pragma unroll
          for (int kk = jj + 1; kk < 16; ++kk) {
            float l = rl(p[jj], j0 + kk);
            p[kk] -= p[jj] * l;
          }
        }
        if (pan == 3) {
          // maskless solves on A (strict-lower, col-scaled): chain = rl + fma only
          float r = y_s[lane];
#pragma unroll 16
          for (int i = 0; i < 64; ++i) {
            float Ai = M_s[lane * 65 + i];       // column i (zero for lane <= i)
            r -= Ai * rl(r, i);
          }
          float tau = r * dinv * dinv;           // into tau-space
#pragma unroll 16
          for (int i = 63; i >= 0; --i) {
            float Bi = M_s[i * 65 + lane];       // row i (zero for lane >= i)
            tau -= Bi * rl(tau, i);
          }
          x_s[lane] = tau;                       // x = tau (no final scale)
        }
      } else if (pan >= 1) {
        // trailRest(pan-1): cols [16*pan+16, 64) w.r.t. panel pan-1 — waves 1..7
        int k0 = 16 * pan + 16;
        if (k0 < 64) {
          float Lrow[16];
#pragma unroll
          for (int jj = 0; jj < 16; ++jj) Lrow[jj] = Lpr[jj * 64 + lane];
          for (int k = k0 + (wv - 1); k < 64; k += 7) {
            float acc = M_s[lane * 65 + k];
#pragma unroll
            for (int jj = 0; jj < 16; ++jj) acc -= Lrow[jj] * Lpr[jj * 64 + k];
            M_s[lane * 65 + k] = acc;
          }
        }
      }
      __syncthreads();
      if (pan < 3) {
        // trailNext(pan): next panel's 16 cols — all 8 waves, 2 cols each
        float Lrow[16];
#pragma unroll
        for (int jj = 0; jj < 16; ++jj) Lrow[jj] = Lpw[jj * 64 + lane];
#pragma unroll
        for (int kk2 = 0; kk2 < 2; ++kk2) {
          int k = j0 + 16 + wv * 2 + kk2;
          float acc = M_s[lane * 65 + k];
#pragma unroll
          for (int jj = 0; jj < 16; ++jj) acc -= Lrow[jj] * Lpw[jj * 64 + k];
          M_s[lane * 65 + k] = acc;
        }
        __syncthreads();
      }
    }
    // ---- E: u = G x from register G + 32-lane butterfly reduce; c,h update ----
    {
      float2 xl = *(const float2*)(x_s + e0);
      float u0[8];
#pragma unroll
      for (int r = 0; r < 8; ++r) u0[r] = gva[0][r] * xl.x + gva[1][r] * xl.y;
#pragma unroll
      for (int sft = 1; sft < 32; sft <<= 1)
#pragma unroll
        for (int r = 0; r < 8; ++r) u0[r] += __shfl_xor(u0[r], sft, 32);
      if (ep == 0) {
        float cn[8], hn[8];
        bf16x8 hh8, hl8;
        unsigned long long h8v = 0ULL;
#pragma unroll
        for (int r = 0; r < 8; ++r) {
          cn[r] = s_s[h0 + r] - EPSP * u0[r];
          hn[r] = o_s[h0 + r] * ftanh(cn[r]);
          __bf16 hi = (__bf16)hn[r];
          hh8[r] = hi; hl8[r] = (__bf16)(hn[r] - (float)hi);
          h8v |= ((unsigned long long)enc8(hn[r] * 16.f)) << (8 * r);
        }
        *(float4*)(c_s + h0)     = (float4){cn[0], cn[1], cn[2], cn[3]};
        *(float4*)(c_s + h0 + 4) = (float4){cn[4], cn[5], cn[6], cn[7]};
        *(float4*)(h_s + h0)     = (float4){hn[0], hn[1], hn[2], hn[3]};
        *(float4*)(h_s + h0 + 4) = (float4){hn[4], hn[5], hn[6], hn[7]};
        *(bf16x8*)(hbH + h0) = hh8;
        *(bf16x8*)(hbL + h0) = hl8;
        *(unsigned long long*)(hb8 + h0) = h8v;
      }
    }
    __syncthreads();
  }
  // ---- head ----
  if (tid < O_) {
    float acc = lin_b[tid];
    for (int hh2 = 0; hh2 < 128; ++hh2) acc += h_s[hh2] * lin_w[tid * 128 + hh2];
    out[(size_t)bb * O_ + tid] = acc;
  }
}

// ---------------- launch ----------------
extern "C" void kernel_launch(void* const* d_in, const int* in_sizes, int n_in,
                              void* d_out, int out_size, void* d_ws, size_t ws_size,
                              hipStream_t stream) {
  (void)in_sizes; (void)n_in; (void)out_size;
  const float* inputs  = (const float*)d_in[0];
  const float* conv_w  = (const float*)d_in[2];
  const float* conv_b  = (const float*)d_in[3];
  const float* gamma   = (const float*)d_in[4];
  const float* beta    = (const float*)d_in[5];
  const float* w_ih    = (const float*)d_in[6];
  const float* w_hh    = (const float*)d_in[7];
  const float* b_ih    = (const float*)d_in[8];
  const float* b_hh    = (const float*)d_in[9];
  const float* lin_w   = (const float*)d_in[10];
  const float* lin_b   = (const float*)d_in[11];
  float* out = (float*)d_out;
  float* ws  = (float*)d_ws;

  if (ws_size < WS_FLOATS * sizeof(float)) return;

  hipLaunchKernelGGL(prep_kernel, dim3(192), dim3(256), 0, stream, conv_w, w_hh, ws);
  hipLaunchKernelGGL(conv_bn_kernel, dim3(1024), dim3(256), 0, stream, inputs, conv_b, ws);
  hipLaunchKernelGGL(bn_finalize_kernel, dim3(1), dim3(64), 0, stream, gamma, beta, ws);
  hipLaunchKernelGGL(zx_kernel, dim3(1024), dim3(256), 0, stream, w_ih, b_ih, b_hh, ws);
  hipLaunchKernelGGL(scan_kernel, dim3(64), dim3(512), 0, stream, w_ih, lin_w, lin_b, ws, out);
}